// Round 13
// baseline (332.608 us; speedup 1.0000x reference)
//
#include <hip/hip_runtime.h>

// Pool255: out = (1/8) * sum of 8 directional cumulative-max pools.
// x: [8,256,128,128] fp32. 2048 blocks (2 waves), one image per block.
//
// Half-image ownership, register-resident partials (R10/R11 structure):
//   wave0 owns real rows 0..63, wave1 owns real rows 64..127.
//   Phase A: each wave runs the TD-style 4-dir sweep over ITS rows in its
//     own view (wave0: identity; wave1: 180-rotated view) -- identical code.
//     Per-pixel 4-dir sums packed fp16x2 into 64 VGPRs (S0..S7, static
//     indexing). Final recurrence state {v,d,a} -> 3 KB LDS carry.
//   lgkm-only barrier (global prefetches stay in flight).
//   Phase B: each wave continues the PARTNER's logical sweep over its own
//     rows (opposite view, seeded from partner's carry), combines with its
//     stored phase-A sums (ds_bpermute 63-l mirror + component swap),
//     NT-stores out. Phase-B x re-reads hit L2/L3 (FETCH ~92 MB total).
//
// R13 vs R11: __launch_bounds__(128, 2). Empirical mapping on this kernel
// family (R10 measured): for 128-thread blocks, arg w -> VGPR cap 512/(2w).
//   w=4 -> cap 64 (R10: spill catastrophe), none -> 256 (R11: 2 waves/SIMD).
//   w=2 -> cap 128: fits the ~115-reg live set with no spill, 4 waves/SIMD.
// Also: phase-B's first ring loads are issued BEFORE the barrier (they don't
// depend on the carry), so B doesn't cold-start on memory.

#define NPIX 16384
#define NEGF (-3.402823466e38f)

typedef __fp16 half2v __attribute__((ext_vector_type(2)));

// dst[l] = src[l -/+ 1]; invalid lanes get `oldv`.
template <int CTRL>
__device__ __forceinline__ float dpp_movf(float oldv, float src) {
  return __int_as_float(__builtin_amdgcn_update_dpp(
      __float_as_int(oldv), __float_as_int(src), CTRL, 0xf, 0xf, false));
}
#define WAVE_SHR1 0x138  // lane l reads lane l-1 (lane 0 -> old)
#define WAVE_SHL1 0x130  // lane l reads lane l+1 (lane 63 -> old)

// y = max(y, dpp_move(y)) ; masked/invalid lanes keep old=y (no-op)
#define DPP_MAXSTEP(y, ctrl, rmask)                                          \
  y = fmaxf(y, __int_as_float(__builtin_amdgcn_update_dpp(                   \
                 __float_as_int(y), __float_as_int(y), ctrl, rmask, 0xf,     \
                 false)))

// Barrier draining only LDS (lgkm) — global prefetches stay in flight.
__device__ __forceinline__ void lds_barrier() {
  asm volatile("s_waitcnt lgkmcnt(0)\n\ts_barrier" ::: "memory");
}

struct Sweep {
  float v0, v1, d0, d1, a0, a1;
};

// One view-row step of the TD-style 4-dir recurrence set; yields the
// per-pixel 4-dir sum (p0 = view col 2l, p1 = view col 2l+1).
template <bool MIR>
__device__ __forceinline__ void row_step(const float2 xv, Sweep& s,
                                         float& p0, float& p1) {
  const float x0 = MIR ? xv.y : xv.x;
  const float x1 = MIR ? xv.x : xv.y;
  s.v0 = fmaxf(s.v0, x0);
  s.v1 = fmaxf(s.v1, x1);
  // diag: D[c] = max(x[c], Dprev[c-1])
  const float pd = dpp_movf<WAVE_SHR1>(NEGF, s.d1);
  const float nd0 = fmaxf(x0, pd);
  const float nd1 = fmaxf(x1, s.d0);
  s.d0 = nd0; s.d1 = nd1;
  // anti: A[c] = max(x[c], Aprev[c+1])
  const float pa = dpp_movf<WAVE_SHL1>(NEGF, s.a0);
  const float na1 = fmaxf(x1, pa);
  const float na0 = fmaxf(x0, s.a1);
  s.a0 = na0; s.a1 = na1;
  // row inclusive prefix-max (DPP scan)
  float y = fmaxf(x0, x1);
  DPP_MAXSTEP(y, 0x111, 0xf);  // row_shr:1
  DPP_MAXSTEP(y, 0x112, 0xf);  // row_shr:2
  DPP_MAXSTEP(y, 0x114, 0xf);  // row_shr:4
  DPP_MAXSTEP(y, 0x118, 0xf);  // row_shr:8
  DPP_MAXSTEP(y, 0x142, 0xa);  // row_bcast15 -> rows 1,3
  DPP_MAXSTEP(y, 0x143, 0xc);  // row_bcast31 -> rows 2,3
  const float ex = dpp_movf<WAVE_SHR1>(NEGF, y);
  const float sc0 = fmaxf(ex, x0);
  p0 = (s.v0 + s.d0) + (s.a0 + sc0);
  p1 = (s.v1 + s.d1) + (s.a1 + y);
}

// Phase A sub-block: 8 view-rows, store packed sums into S. Ring depth 4.
template <bool MIR>
__device__ __forceinline__ void subA(unsigned (&S)[8], const int tb,
                                     const float* __restrict__ base,
                                     float2 (&G)[4], Sweep& s) {
  constexpr int RS = MIR ? -128 : 128;
#pragma unroll
  for (int k = 0; k < 8; ++k) {
    const float2 xv = G[k & 3];
    G[k & 3] = *(const float2*)(base + (ptrdiff_t)(tb + k + 4) * RS);
    float p0, p1;
    row_step<MIR>(xv, s, p0, p1);
    const half2v h = __builtin_amdgcn_cvt_pkrtz(p0, p1);
    S[k] = __builtin_bit_cast(unsigned, h);
  }
}

// Phase B sub-block: 8 view-rows (rows 64..127 of the OPPOSITE view),
// combine with mirrored stored sums, NT-store final output.
template <bool MIR>
__device__ __forceinline__ void subB(unsigned (&S)[8], const int tb,
                                     const float* __restrict__ base,
                                     float* __restrict__ oim, const int off,
                                     const int addr_rev, float2 (&G)[4],
                                     Sweep& s) {
  constexpr int RS = MIR ? -128 : 128;
#pragma unroll
  for (int k = 0; k < 8; ++k) {
    const int t = tb + k;
    const float2 xv = G[k & 3];
    const int tp = (t + 4 < 128) ? (t + 4) : 127;  // clamp (uniform)
    G[k & 3] = *(const float2*)(base + (ptrdiff_t)tp * RS);
    // partner-lane (63-l) phase-A sum for this real pixel pair
    const unsigned q =
        (unsigned)__builtin_amdgcn_ds_bpermute(addr_rev, (int)S[7 - k]);
    float p0, p1;
    row_step<MIR>(xv, s, p0, p1);
    const half2v hq = __builtin_bit_cast(half2v, q);
    const float o0 = (p0 + (float)hq.y) * 0.125f;  // view col 2l   <- src p1
    const float o1 = (p1 + (float)hq.x) * 0.125f;  // view col 2l+1 <- src p0
    const int row = MIR ? 127 - t : t;
    const float2 ov = MIR ? make_float2(o1, o0) : make_float2(o0, o1);
    __builtin_nontemporal_store(
        __builtin_bit_cast(unsigned long long, ov),
        (unsigned long long*)(oim + (row << 7) + off));
  }
}

template <bool MIRA>
__device__ __forceinline__ void wave_run(const float* __restrict__ xim,
                                         float* __restrict__ oim,
                                         float2 (*carry)[3][64], const int l) {
  constexpr bool MIRB = !MIRA;
  constexpr int wid = MIRA ? 1 : 0;
  Sweep s{NEGF, NEGF, NEGF, NEGF, NEGF, NEGF};
  unsigned S0[8], S1[8], S2[8], S3[8], S4[8], S5[8], S6[8], S7[8];
  float2 G[4];

  // ---- phase A: own half, own view, rows 0..63 ----
  {
    constexpr int RS = MIRA ? -128 : 128;
    const int off = MIRA ? (63 - l) * 2 : l * 2;
    const float* __restrict__ base = xim + off + (MIRA ? 127 * 128 : 0);
#pragma unroll
    for (int k = 0; k < 4; ++k)
      G[k] = *(const float2*)(base + (ptrdiff_t)k * RS);
    subA<MIRA>(S0, 0, base, G, s);
    subA<MIRA>(S1, 8, base, G, s);
    subA<MIRA>(S2, 16, base, G, s);
    subA<MIRA>(S3, 24, base, G, s);
    subA<MIRA>(S4, 32, base, G, s);
    subA<MIRA>(S5, 40, base, G, s);
    subA<MIRA>(S6, 48, base, G, s);
    subA<MIRA>(S7, 56, base, G, s);
    carry[wid][0][l] = make_float2(s.v0, s.v1);
    carry[wid][1][l] = make_float2(s.d0, s.d1);
    carry[wid][2][l] = make_float2(s.a0, s.a1);
  }

  // ---- pre-issue phase-B's first ring loads (carry-independent) ----
  constexpr int RSB = MIRB ? -128 : 128;
  const int offB = MIRB ? (63 - l) * 2 : l * 2;
  const float* __restrict__ baseB = xim + offB + (MIRB ? 127 * 128 : 0);
#pragma unroll
  for (int k = 0; k < 4; ++k)
    G[k] = *(const float2*)(baseB + (ptrdiff_t)(64 + k) * RSB);

  lds_barrier();  // carries visible; x prefetches stay in flight

  // ---- phase B: own half, OPPOSITE view rows 64..127, seeded ----
  {
    const float2 cv = carry[1 - wid][0][l];
    const float2 cd = carry[1 - wid][1][l];
    const float2 ca = carry[1 - wid][2][l];
    s.v0 = cv.x; s.v1 = cv.y;
    s.d0 = cd.x; s.d1 = cd.y;
    s.a0 = ca.x; s.a1 = ca.y;
    const int addr_rev = (63 - l) * 4;
    subB<MIRB>(S7, 64, baseB, oim, offB, addr_rev, G, s);
    subB<MIRB>(S6, 72, baseB, oim, offB, addr_rev, G, s);
    subB<MIRB>(S5, 80, baseB, oim, offB, addr_rev, G, s);
    subB<MIRB>(S4, 88, baseB, oim, offB, addr_rev, G, s);
    subB<MIRB>(S3, 96, baseB, oim, offB, addr_rev, G, s);
    subB<MIRB>(S2, 104, baseB, oim, offB, addr_rev, G, s);
    subB<MIRB>(S1, 112, baseB, oim, offB, addr_rev, G, s);
    subB<MIRB>(S0, 120, baseB, oim, offB, addr_rev, G, s);
  }
}

__global__ __launch_bounds__(128, 2) void pool255_half(
    const float* __restrict__ x, float* __restrict__ out) {
  __shared__ float2 carry[2][3][64];  // 3 KB
  const int img = blockIdx.x;
  const float* __restrict__ xim = x + (size_t)img * NPIX;
  float* __restrict__ oim = out + (size_t)img * NPIX;
  const int l = threadIdx.x & 63;
  if (threadIdx.x < 64)
    wave_run<false>(xim, oim, carry, l);  // rows 0..63, TD first
  else
    wave_run<true>(xim, oim, carry, l);   // rows 64..127, BU first
}

extern "C" void kernel_launch(void* const* d_in, const int* in_sizes, int n_in,
                              void* d_out, int out_size, void* d_ws,
                              size_t ws_size, hipStream_t stream) {
  const float* x = (const float*)d_in[0];
  float* out = (float*)d_out;
  const int n_img = in_sizes[0] / NPIX;  // 8*256 = 2048
  pool255_half<<<n_img, 128, 0, stream>>>(x, out);
}

// Round 14
// 76.022 us; speedup vs baseline: 4.3752x; 4.3752x over previous
//
#include <hip/hip_runtime.h>

// Pool255: out = (1/8) * sum of 8 directional cumulative-max pools.
// x: [8,256,128,128] fp32. 2048 blocks x 256 thr (4 waves = 4 row-quarters
// of one image). NO barriers, NO cross-wave exchange.
//
// Wave q owns real rows a..a+31, a = 32q. It is fully self-contained:
//  TD context (identity view): sweep view-rows 0..a+31; rows < a are
//    state-only "cheap" steps (v/d/a recurrences, ~9 ops); rows a..a+31 run
//    the full 4-dir body (R8 phase-0) storing fp16x2 partials into the
//    wave's PRIVATE 8 KB LDS quarter.
//  BU context (180-rotated MIR view): sweep view-rows 0..127-a; rows
//    < 96-a cheap; last 32 run the full combine body (R8 phase-1 mapping:
//    slot 63-l, hq.y/hq.x swap, reversed part row index), NT-store out.
// Seeding is by continuation -- the state entering the full section is the
// exact full-image prefix state. Every wave: (a+32)+(128-a) = 160 steps.
//
// Occupancy: 32 KB LDS/block but tiny VGPR footprint (no S-arrays) ->
// 4-5 blocks/CU = 16-20 waves/CU vs R8's 10, at ~1.3x VALU. Extra x
// re-reads are shared by the 4 same-CU waves -> L1/L2 hits.

#define NPIX 16384
#define NEGF (-3.402823466e38f)

typedef __fp16 half2v __attribute__((ext_vector_type(2)));

// dst[l] = src[l -/+ 1]; invalid lanes get `oldv`.
template <int CTRL>
__device__ __forceinline__ float dpp_movf(float oldv, float src) {
  return __int_as_float(__builtin_amdgcn_update_dpp(
      __float_as_int(oldv), __float_as_int(src), CTRL, 0xf, 0xf, false));
}
#define WAVE_SHR1 0x138  // lane l reads lane l-1 (lane 0 -> old)
#define WAVE_SHL1 0x130  // lane l reads lane l+1 (lane 63 -> old)

// y = max(y, dpp_move(y)) ; masked/invalid lanes keep old=y (no-op)
#define DPP_MAXSTEP(y, ctrl, rmask)                                          \
  y = fmaxf(y, __int_as_float(__builtin_amdgcn_update_dpp(                   \
                 __float_as_int(y), __float_as_int(y), ctrl, rmask, 0xf,     \
                 false)))

struct Sweep {
  float v0, v1, d0, d1, a0, a1;
};

// v/d/a recurrences only (state carry), ~9 VALU ops.
template <bool MIR>
__device__ __forceinline__ void cheap_step(const float2 xv, Sweep& s) {
  const float x0 = MIR ? xv.y : xv.x;
  const float x1 = MIR ? xv.x : xv.y;
  s.v0 = fmaxf(s.v0, x0);
  s.v1 = fmaxf(s.v1, x1);
  const float pd = dpp_movf<WAVE_SHR1>(NEGF, s.d1);
  const float nd0 = fmaxf(x0, pd);
  const float nd1 = fmaxf(x1, s.d0);
  s.d0 = nd0; s.d1 = nd1;
  const float pa = dpp_movf<WAVE_SHL1>(NEGF, s.a0);
  const float na1 = fmaxf(x1, pa);
  const float na0 = fmaxf(x0, s.a1);
  s.a0 = na0; s.a1 = na1;
}

// Full step: v/d/a + DPP prefix scan; yields 4-dir sum (view cols 2l,2l+1).
template <bool MIR>
__device__ __forceinline__ void row_step(const float2 xv, Sweep& s,
                                         float& p0, float& p1) {
  const float x0 = MIR ? xv.y : xv.x;
  const float x1 = MIR ? xv.x : xv.y;
  s.v0 = fmaxf(s.v0, x0);
  s.v1 = fmaxf(s.v1, x1);
  const float pd = dpp_movf<WAVE_SHR1>(NEGF, s.d1);
  const float nd0 = fmaxf(x0, pd);
  const float nd1 = fmaxf(x1, s.d0);
  s.d0 = nd0; s.d1 = nd1;
  const float pa = dpp_movf<WAVE_SHL1>(NEGF, s.a0);
  const float na1 = fmaxf(x1, pa);
  const float na0 = fmaxf(x0, s.a1);
  s.a0 = na0; s.a1 = na1;
  float y = fmaxf(x0, x1);
  DPP_MAXSTEP(y, 0x111, 0xf);  // row_shr:1
  DPP_MAXSTEP(y, 0x112, 0xf);  // row_shr:2
  DPP_MAXSTEP(y, 0x114, 0xf);  // row_shr:4
  DPP_MAXSTEP(y, 0x118, 0xf);  // row_shr:8
  DPP_MAXSTEP(y, 0x142, 0xa);  // row_bcast15 -> rows 1,3
  DPP_MAXSTEP(y, 0x143, 0xc);  // row_bcast31 -> rows 2,3
  const float ex = dpp_movf<WAVE_SHR1>(NEGF, y);
  const float sc0 = fmaxf(ex, x0);
  p0 = (s.v0 + s.d0) + (s.a0 + sc0);
  p1 = (s.v1 + s.d1) + (s.a1 + y);
}

__device__ __forceinline__ void quarter_run(const float* __restrict__ xim,
                                            float* __restrict__ oim,
                                            unsigned* __restrict__ part,
                                            const int l, const int a) {
  // ================= TD context: identity view =================
  {
    const int off = l * 2;
    const float* __restrict__ base = xim + off;
    Sweep s{NEGF, NEGF, NEGF, NEGF, NEGF, NEGF};
    float2 G[4];
#pragma unroll
    for (int k = 0; k < 4; ++k)
      G[k] = *(const float2*)(base + (ptrdiff_t)k * 128);
    // cheap: view-rows 0..a-1  (a is 0/32/64/96, wave-uniform)
    for (int vb = 0; vb < a; vb += 8) {
#pragma unroll
      for (int k = 0; k < 8; ++k) {
        const int vr = vb + k;
        const float2 xv = G[vr & 3];
        G[vr & 3] = *(const float2*)(base + (ptrdiff_t)(vr + 4) * 128);
        cheap_step<false>(xv, s);
      }
    }
    // full: view-rows a..a+31, store partials to private LDS
    for (int vb = a; vb < a + 32; vb += 8) {
#pragma unroll
      for (int k = 0; k < 8; ++k) {
        const int vr = vb + k;
        const float2 xv = G[vr & 3];
        const int tp = (vr + 4 < a + 32) ? (vr + 4) : (a + 31);  // clamp
        G[vr & 3] = *(const float2*)(base + (ptrdiff_t)tp * 128);
        float p0, p1;
        row_step<false>(xv, s, p0, p1);
        const half2v h = __builtin_amdgcn_cvt_pkrtz(p0, p1);
        part[((vr - a) << 6) | l] = __builtin_bit_cast(unsigned, h);
      }
    }
  }

  // drain LDS writes before same-wave reads (no barrier needed: private)
  asm volatile("s_waitcnt lgkmcnt(0)" ::: "memory");

  // ================= BU context: MIR view (180 rot) =================
  {
    const int off = (63 - l) * 2;
    const float* __restrict__ base = xim + off + 127 * 128;  // view row 0
    Sweep s{NEGF, NEGF, NEGF, NEGF, NEGF, NEGF};
    const int nc = 96 - a;  // cheap count; full covers real rows a..a+31
    float2 G[4];
#pragma unroll
    for (int k = 0; k < 4; ++k)
      G[k] = *(const float2*)(base - (ptrdiff_t)k * 128);
    // cheap: view-rows 0..nc-1 (real rows 127..a+32)
    for (int vb = 0; vb < nc; vb += 8) {
#pragma unroll
      for (int k = 0; k < 8; ++k) {
        const int vr = vb + k;
        const float2 xv = G[vr & 3];
        G[vr & 3] = *(const float2*)(base - (ptrdiff_t)(vr + 4) * 128);
        cheap_step<true>(xv, s);
      }
    }
    // full: view-rows nc..nc+31 (real rows a+31..a), combine + NT-store
    for (int vb = nc; vb < nc + 32; vb += 8) {
#pragma unroll
      for (int k = 0; k < 8; ++k) {
        const int vr = vb + k;
        const float2 xv = G[vr & 3];
        const int tp = (vr + 4 < nc + 32) ? (vr + 4) : (nc + 31);  // clamp
        G[vr & 3] = *(const float2*)(base - (ptrdiff_t)tp * 128);
        const int rrow = 127 - vr;          // real row, in [a, a+31]
        const unsigned q = part[((rrow - a) << 6) | (63 - l)];
        float p0, p1;
        row_step<true>(xv, s, p0, p1);
        const half2v hq = __builtin_bit_cast(half2v, q);
        const float o0 = (p0 + (float)hq.y) * 0.125f;  // view col 2l
        const float o1 = (p1 + (float)hq.x) * 0.125f;  // view col 2l+1
        const float2 ov = make_float2(o1, o0);
        __builtin_nontemporal_store(
            __builtin_bit_cast(unsigned long long, ov),
            (unsigned long long*)(oim + (rrow << 7) + off));
      }
    }
  }
}

__global__ __launch_bounds__(256) void pool255_quarter(
    const float* __restrict__ x, float* __restrict__ out) {
  __shared__ unsigned part[4][32 * 64];  // 4 x 8 KB, wave-private quarters
  const int img = blockIdx.x;
  const float* __restrict__ xim = x + (size_t)img * NPIX;
  float* __restrict__ oim = out + (size_t)img * NPIX;
  const int qid = threadIdx.x >> 6;  // 0..3 -> rows 32q..32q+31
  const int l = threadIdx.x & 63;
  quarter_run(xim, oim, part[qid], l, qid * 32);
}

extern "C" void kernel_launch(void* const* d_in, const int* in_sizes, int n_in,
                              void* d_out, int out_size, void* d_ws,
                              size_t ws_size, hipStream_t stream) {
  const float* x = (const float*)d_in[0];
  float* out = (float*)d_out;
  const int n_img = in_sizes[0] / NPIX;  // 8*256 = 2048
  pool255_quarter<<<n_img, 256, 0, stream>>>(x, out);
}